// Round 13
// baseline (466.766 us; speedup 1.0000x reference)
//
#include <hip/hip_runtime.h>

// MHA forward, MI355X/gfx950 — round 13.
// Base = R11 (best, 367.9us). Single change (pass-2 store decoupling):
//   Probs values stashed in B (pst[2][4], +32 VGPR) and the 8 nt stores moved
//   to phase G AFTER stageV(tt+1). FIFO effect: at B1 the V-guard vmcnt(12)
//   keeps {stores(tt-1), K(tt+1)} — stores are NEWER than V(tt) and are no
//   longer drained at the barrier'd B1. Store retirement is absorbed at the
//   per-wave top-of-iter wait instead of blocking all 4 waves before PV.
// Kept: XCD swizzle, exp2 builtin, nt stores, 3 blocks/CU, pass-1 3-deep ring,
//       single-K-buffer pass 2, wave-private K staging.

#define DEV __device__ __forceinline__

typedef __attribute__((ext_vector_type(8))) short short8;   // 8 bf16 (MFMA A/B frag)
typedef __attribute__((ext_vector_type(4))) float f32x4;    // MFMA C/D frag

DEV unsigned short f2b(float f) {   // f32 -> bf16 RNE
  union { float f; unsigned u; } v; v.f = f;
  unsigned r = v.u + 0x7fffu + ((v.u >> 16) & 1u);
  return (unsigned short)(r >> 16);
}
DEV unsigned pk2(float lo, float hi) {  // two f32 -> packed bf16x2
  return (unsigned)f2b(lo) | ((unsigned)f2b(hi) << 16);
}
#if __has_builtin(__builtin_amdgcn_exp2f)
DEV float exp2_fast(float x) { return __builtin_amdgcn_exp2f(x); }
#else
DEV float exp2_fast(float x) { return exp2f(x); }
#endif
DEV void gl_lds16(const void* g, void* l) {  // async global->LDS, dest = base + lane*16
  __builtin_amdgcn_global_load_lds(
      (const __attribute__((address_space(1))) void*)g,
      (__attribute__((address_space(3))) void*)l, 16, 0, 0);
}
DEV void bar_lgkm() { asm volatile("s_waitcnt lgkmcnt(0)\n\ts_barrier" ::: "memory"); }

__global__ void cvt_f32_bf16(const float* __restrict__ src, unsigned short* __restrict__ dst, int n) {
  int i = (blockIdx.x * blockDim.x + threadIdx.x) * 4;
  if (i >= n) return;
  float4 v = *(const float4*)(src + i);
  ushort4 o; o.x = f2b(v.x); o.y = f2b(v.y); o.z = f2b(v.z); o.w = f2b(v.w);
  *(ushort4*)(dst + i) = o;
}

// C = A @ B^T + bias; A[M][K], B[N][K] bf16. 128x128 tile, BK=64, 4 waves (2x2).
template<int MODE>
__global__ __launch_bounds__(256, 2) void gemm_bt(
    const unsigned short* __restrict__ A,
    const unsigned short* __restrict__ B,
    const float* __restrict__ bias,
    float* __restrict__ Cf,
    unsigned short* __restrict__ Cqk,
    unsigned short* __restrict__ Vtg,
    int N, int K)
{
  constexpr int BK = 64;
  __shared__ __align__(16) unsigned short As[128*BK];
  __shared__ __align__(16) unsigned short Bs[128*BK];
  const int tid = threadIdx.x, lane = tid & 63, wid = tid >> 6;
  const int lhi = lane >> 4, llo = lane & 15;
  const int m0 = blockIdx.y * 128, n0 = blockIdx.x * 128;
  const int wr = wid >> 1, wc = wid & 1;

  f32x4 acc[4][4] = {};

  const int nsteps = K / BK;
  for (int kt = 0; kt < nsteps; ++kt) {
    __syncthreads();
#pragma unroll
    for (int s = 0; s < 4; ++s) {
      int u = wid*4 + s;
      int a = u*1024 + lane*16;
      int t = a >> 7;
      int cb = (a & 127) ^ ((t & 7) << 4);
      int e = kt*BK + (cb >> 1);
      gl_lds16(A + (size_t)(m0 + t)*K + e, (char*)As + u*1024);
      gl_lds16(B + (size_t)(n0 + t)*K + e, (char*)Bs + u*1024);
    }
    __syncthreads();
#pragma unroll
    for (int kk = 0; kk < 2; ++kk) {
      short8 af[4], bfr[4];
#pragma unroll
      for (int mf = 0; mf < 4; ++mf) {
        int row = wr*64 + mf*16 + llo;
        af[mf] = *(const short8*)((const char*)As + row*128 + ((kk*64 + lhi*16) ^ ((row & 7) << 4)));
      }
#pragma unroll
      for (int nf = 0; nf < 4; ++nf) {
        int row = wc*64 + nf*16 + llo;
        bfr[nf] = *(const short8*)((const char*)Bs + row*128 + ((kk*64 + lhi*16) ^ ((row & 7) << 4)));
      }
#pragma unroll
      for (int mf = 0; mf < 4; ++mf)
#pragma unroll
        for (int nf = 0; nf < 4; ++nf)
          acc[mf][nf] = __builtin_amdgcn_mfma_f32_16x16x32_bf16(af[mf], bfr[nf], acc[mf][nf], 0, 0, 0);
    }
  }
  if (MODE == 0) {
#pragma unroll
    for (int mf = 0; mf < 4; ++mf)
#pragma unroll
      for (int nf = 0; nf < 4; ++nf) {
        int n = n0 + wc*64 + nf*16 + llo;
        float bv = bias[n];
#pragma unroll
        for (int r = 0; r < 4; ++r) {
          int m = m0 + wr*64 + mf*16 + lhi*4 + r;
          __builtin_nontemporal_store(acc[mf][nf][r] + bv, &Cf[(size_t)m*N + n]);
        }
      }
  } else {
    if (n0 < 2048) {  // Q/K region
#pragma unroll
      for (int mf = 0; mf < 4; ++mf)
#pragma unroll
        for (int nf = 0; nf < 4; ++nf) {
          int n = n0 + wc*64 + nf*16 + llo;
          float bv = bias[n];
          float sc = (n < 1024) ? 0.125f * 1.44269504088896f : 1.0f;
#pragma unroll
          for (int r = 0; r < 4; ++r) {
            int m = m0 + wr*64 + mf*16 + lhi*4 + r;
            Cqk[(size_t)m*2048 + n] = f2b((acc[mf][nf][r] + bv) * sc);
          }
        }
    } else {          // V region -> transposed Vtg[bh][d][t]
#pragma unroll
      for (int mf = 0; mf < 4; ++mf)
#pragma unroll
        for (int nf = 0; nf < 4; ++nf) {
          int n = n0 + wc*64 + nf*16 + llo;
          float bv = bias[n];
          int hh = (n - 2048) >> 6, d = (n - 2048) & 63;
          int m = m0 + wr*64 + mf*16 + lhi*4;
          int bb = m >> 11, t = m & 2047;
          ushort4 o;
          o.x = f2b(acc[mf][nf][0] + bv);
          o.y = f2b(acc[mf][nf][1] + bv);
          o.z = f2b(acc[mf][nf][2] + bv);
          o.w = f2b(acc[mf][nf][3] + bv);
          *(ushort4*)(Vtg + ((size_t)((bb << 4) + hh)*64 + d)*2048 + t) = o;
        }
    }
  }
}

// Fused attention. Block = (b,h,qt): 64 q-rows, 4 waves, 3 blocks/CU.
__global__ __launch_bounds__(256, 3) void mha_fused(
    const unsigned short* __restrict__ qk,    // [8192][2048] bf16 (q scaled)
    const unsigned short* __restrict__ vtg,   // [64 bh][64 d][2048 t] bf16
    float* __restrict__ probs,                // [64 bh][2048][2048] f32
    unsigned short* __restrict__ attnb)       // [8192][1024] bf16
{
  constexpr int T = 2048, LD = 2048, QB = 64, TB = 128, NT = T / TB;
  __shared__ __align__(16) unsigned short Kslot[TB*64];   // 16 KB (ring0; pass2 K)
  __shared__ __align__(16) unsigned short Vslot[64*TB];   // 16 KB (ring1; pass2 V)
  __shared__ __align__(16) unsigned short Ps[QB*TB];      // 16 KB (ring2; Q prologue; pass2 P)
  __shared__ float lsum[4][QB];
  __shared__ float linv[QB];

  const int tid = threadIdx.x, lane = tid & 63, wid = tid >> 6;
  const int lhi = lane >> 4, llo = lane & 15;
  const int wg = ((blockIdx.x & 7) << 8) | (blockIdx.x >> 3);   // XCD swizzle
  const int qt = wg & 31, bh = wg >> 5;
  const int bb = bh >> 4, h = bh & 15;
  const int q0 = qt * QB;
  const size_t tokQ = (size_t)bb*T + q0;

  auto stageK = [&](int tt, unsigned short* buf) {
#pragma unroll
    for (int s = 0; s < 4; ++s) {
      int u = wid*4 + s;
      int a = u*1024 + lane*16;
      int tr = a >> 7;
      int cb = (a & 127) ^ ((tr & 7) << 4);
      gl_lds16(qk + ((size_t)bb*T + tt*TB + tr)*LD + 1024 + h*64 + (cb >> 1),
               (char*)buf + u*1024);
    }
  };
  auto stageV = [&](int tt) {
#pragma unroll
    for (int s = 0; s < 4; ++s) {
      int u = wid*4 + s;
      int a = u*1024 + lane*16;
      int d = a >> 8;
      int cb = (a & 255) ^ ((d & 7) << 4);
      gl_lds16(vtg + ((size_t)bh*64 + d)*T + tt*TB + (cb >> 1),
               (char*)Vslot + u*1024);
    }
  };
  auto bsel = [&](int m) -> unsigned short* {
    return (m == 0) ? Kslot : ((m == 1) ? Vslot : Ps);
  };

  // ---- prologue: Q (into Ps, 2/wave) + K0->Kslot + K1->Vslot ----
#pragma unroll
  for (int s = 0; s < 2; ++s) {
    int u = wid*2 + s;
    int a = u*1024 + lane*16;
    int tr = a >> 7;
    int cb = (a & 127) ^ ((tr & 7) << 4);
    gl_lds16(qk + (tokQ + tr)*LD + h*64 + (cb >> 1), (char*)Ps + u*1024);
  }
  stageK(0, Kslot);
  stageK(1, Vslot);
  asm volatile("s_waitcnt vmcnt(8)" ::: "memory");   // own Q done (K0,K1 in flight)
  __builtin_amdgcn_s_barrier();                      // publish Q

  short8 qfr[4][2];
#pragma unroll
  for (int qf = 0; qf < 4; ++qf)
#pragma unroll
    for (int kk = 0; kk < 2; ++kk) {
      int row = qf*16 + llo;
      qfr[qf][kk] = *(const short8*)((const char*)Ps + row*128 + ((kk*64 + lhi*16) ^ ((row & 7) << 4)));
    }
  bar_lgkm();   // all waves done reading Q before ring stages K2 into Ps

  // ---------------- pass 1: denominators (3-deep rolled ring, no barriers) ----------------
  float part[4] = {0.f, 0.f, 0.f, 0.f};
  int m3 = 0, s3 = 2;
  for (int tt = 0; tt < NT; ++tt) {
    if (tt + 2 < NT) stageK(tt + 2, bsel(s3));
    if (tt + 2 < NT)      asm volatile("s_waitcnt vmcnt(8)" ::: "memory");
    else if (tt + 1 < NT) asm volatile("s_waitcnt vmcnt(4)" ::: "memory");
    else                  asm volatile("s_waitcnt vmcnt(0)" ::: "memory");
    const unsigned short* cur = bsel(m3);
    f32x4 sacc[2][4] = {};
#pragma unroll
    for (int kk = 0; kk < 2; ++kk) {
      short8 kf[2];
#pragma unroll
      for (int tf = 0; tf < 2; ++tf) {
        int row = wid*32 + tf*16 + llo;
        kf[tf] = *(const short8*)((const char*)cur + row*128 + ((kk*64 + lhi*16) ^ ((row & 7) << 4)));
      }
#pragma unroll
      for (int tf = 0; tf < 2; ++tf)
#pragma unroll
        for (int qf = 0; qf < 4; ++qf)
          sacc[tf][qf] = __builtin_amdgcn_mfma_f32_16x16x32_bf16(kf[tf], qfr[qf][kk], sacc[tf][qf], 0, 0, 0);
    }
#pragma unroll
    for (int tf = 0; tf < 2; ++tf)
#pragma unroll
      for (int qf = 0; qf < 4; ++qf)
#pragma unroll
        for (int r = 0; r < 4; ++r)
          part[qf] += exp2_fast(sacc[tf][qf][r]);
    m3 = (m3 + 1 == 3) ? 0 : m3 + 1;
    s3 = (s3 + 1 == 3) ? 0 : s3 + 1;
  }

  // reduce denominators
#pragma unroll
  for (int qf = 0; qf < 4; ++qf) {
    float v = part[qf];
    v += __shfl_xor(v, 16);
    v += __shfl_xor(v, 32);
    if (lhi == 0) lsum[wid][qf*16 + llo] = v;
  }
  bar_lgkm();
  if (tid < QB) linv[tid] = 1.0f / (lsum[0][tid] + lsum[1][tid] + lsum[2][tid] + lsum[3][tid]);
  stageK(0, Kslot);                           // K0 for pass 2
  stageV(0);                                  // V0 for pass 2
  bar_lgkm();                                 // linv visible (K0,V0 in flight)
  float lr[4];
#pragma unroll
  for (int qf = 0; qf < 4; ++qf) lr[qf] = linv[qf*16 + llo];

  // ---------------- pass 2: probs + PV (stores issued LAST each iter) ----------------
  f32x4 pv[4] = {};
  f32x4 pst[2][4];
  for (int tt = 0; tt < NT; ++tt) {
    // top: own K(tt) landed. Steady: keep V(tt)4 + stores(tt-1)8 = 12.
    if (tt == 0) asm volatile("s_waitcnt vmcnt(4)"  ::: "memory");
    else         asm volatile("s_waitcnt vmcnt(12)" ::: "memory");
    // A: scores from own Kslot rows
    f32x4 sacc[2][4] = {};
#pragma unroll
    for (int kk = 0; kk < 2; ++kk) {
      short8 kf[2];
#pragma unroll
      for (int tf = 0; tf < 2; ++tf) {
        int row = wid*32 + tf*16 + llo;
        kf[tf] = *(const short8*)((const char*)Kslot + row*128 + ((kk*64 + lhi*16) ^ ((row & 7) << 4)));
      }
#pragma unroll
      for (int tf = 0; tf < 2; ++tf)
#pragma unroll
        for (int qf = 0; qf < 4; ++qf)
          sacc[tf][qf] = __builtin_amdgcn_mfma_f32_16x16x32_bf16(kf[tf], qfr[qf][kk], sacc[tf][qf], 0, 0, 0);
    }
    // own ds_reads complete, then overwrite own K rows with K(tt+1)
    asm volatile("s_waitcnt lgkmcnt(0)" ::: "memory");
    __builtin_amdgcn_sched_barrier(0);
    stageK((tt + 1) & 15, Kslot);                    // dummy wrap at tt=15
    // B: exp2, normalize, pack Ps (LDS), STASH probs (no global stores here)
#pragma unroll
    for (int tf = 0; tf < 2; ++tf)
#pragma unroll
      for (int qf = 0; qf < 4; ++qf) {
        float p0 = exp2_fast(sacc[tf][qf][0]) * lr[qf];
        float p1 = exp2_fast(sacc[tf][qf][1]) * lr[qf];
        float p2 = exp2_fast(sacc[tf][qf][2]) * lr[qf];
        float p3 = exp2_fast(sacc[tf][qf][3]) * lr[qf];
        int q = qf*16 + llo;
        int t0 = wid*32 + tf*16 + lhi*4;
        uint2 w2; w2.x = pk2(p0, p1); w2.y = pk2(p2, p3);
        *(uint2*)((char*)Ps + q*256 + ((t0*2) ^ ((q & 7) << 4))) = w2;
        f32x4 pv4; pv4[0] = 8.f*p0; pv4[1] = 8.f*p1; pv4[2] = 8.f*p2; pv4[3] = 8.f*p3;
        pst[tf][qf] = pv4;
      }
    // B1: V(tt) landed; keep {stores(tt-1)8 + K(tt+1)4} = 12 — stores NOT drained
    if (tt == 0) asm volatile("s_waitcnt vmcnt(4) lgkmcnt(0)\n\ts_barrier" ::: "memory");
    else         asm volatile("s_waitcnt vmcnt(12) lgkmcnt(0)\n\ts_barrier" ::: "memory");
    // D: PV (reads Ps + Vslot)
#pragma unroll
    for (int kk2 = 0; kk2 < 4; ++kk2) {
      int rq = wid*16 + llo;
      short8 pb = *(const short8*)((const char*)Ps + rq*256 + ((kk2*64 + lhi*16) ^ ((rq & 7) << 4)));
#pragma unroll
      for (int mf = 0; mf < 4; ++mf) {
        int rd = mf*16 + llo;
        short8 va = *(const short8*)((const char*)Vslot + rd*256 + ((kk2*64 + lhi*16) ^ ((rd & 7) << 4)));
        pv[mf] = __builtin_amdgcn_mfma_f32_16x16x32_bf16(va, pb, pv[mf], 0, 0, 0);
      }
    }
    // B2: all waves done with Ps/Vslot before overwrite next iter
    asm volatile("s_waitcnt lgkmcnt(0)\n\ts_barrier" ::: "memory");
    // F: issue next V
    stageV((tt + 1) & 15);                           // dummy wrap at tt=15
    asm volatile("" ::: "memory");
    // G: probs stores — newest VMEM this iteration (never barrier-drained)
#pragma unroll
    for (int tf = 0; tf < 2; ++tf)
#pragma unroll
      for (int qf = 0; qf < 4; ++qf) {
        int q = qf*16 + llo;
        int t0 = wid*32 + tf*16 + lhi*4;
        __builtin_nontemporal_store(pst[tf][qf],
            (f32x4*)&probs[((size_t)bh*T + q0 + q)*T + tt*TB + t0]);
      }
  }

  // attn out: D[d][q], lane has 4 consecutive d at q = wid*16+llo
#pragma unroll
  for (int mf = 0; mf < 4; ++mf) {
    int q = wid*16 + llo;
    int d0 = mf*16 + lhi*4;
    ushort4 o;
    o.x = f2b(pv[mf][0]); o.y = f2b(pv[mf][1]);
    o.z = f2b(pv[mf][2]); o.w = f2b(pv[mf][3]);
    *(ushort4*)(attnb + (tokQ + q)*1024 + h*64 + d0) = o;
  }
}

extern "C" void kernel_launch(void* const* d_in, const int* in_sizes, int n_in,
                              void* d_out, int out_size, void* d_ws, size_t ws_size,
                              hipStream_t stream) {
  (void)in_sizes; (void)n_in; (void)out_size; (void)ws_size;
  const float* x    = (const float*)d_in[0];
  const float* wqkv = (const float*)d_in[1];
  const float* bqkv = (const float*)d_in[2];
  const float* wout = (const float*)d_in[3];
  const float* bout = (const float*)d_in[4];

  constexpr int T = 2048, E = 1024;
  constexpr int M = 4 * T;
  constexpr size_t NX   = (size_t)M * E;
  constexpr size_t NW1  = (size_t)3 * E * E;
  constexpr size_t NW2  = (size_t)E * E;
  constexpr size_t NQK  = (size_t)M * 2048;
  constexpr size_t NVT  = (size_t)64 * 64 * T;

  char* ws = (char*)d_ws;
  unsigned short* xb    = (unsigned short*)ws;  ws += NX  * 2;
  unsigned short* wqkvb = (unsigned short*)ws;  ws += NW1 * 2;
  unsigned short* woutb = (unsigned short*)ws;  ws += NW2 * 2;
  unsigned short* qkb   = (unsigned short*)ws;  ws += NQK * 2;
  unsigned short* vtg   = (unsigned short*)ws;  ws += NVT * 2;
  unsigned short* attnb = (unsigned short*)ws;  ws += NX  * 2;

  cvt_f32_bf16<<<(int)(NX  / 1024), 256, 0, stream>>>(x,    xb,    (int)NX);
  cvt_f32_bf16<<<(int)(NW1 / 1024), 256, 0, stream>>>(wqkv, wqkvb, (int)NW1);
  cvt_f32_bf16<<<(int)(NW2 / 1024), 256, 0, stream>>>(wout, woutb, (int)NW2);

  gemm_bt<1><<<dim3(3*E/128, M/128), 256, 0, stream>>>(
      xb, wqkvb, bqkv, nullptr, qkb, vtg, 3*E, E);

  float* probsOut = (float*)d_out + NX;
  mha_fused<<<4*16*(T/64), 256, 0, stream>>>(qkb, vtg, probsOut, attnb);

  gemm_bt<0><<<dim3(E/128, M/128), 256, 0, stream>>>(
      attnb, woutb, bout, (float*)d_out, nullptr, nullptr, E, E);
}

// Round 14
// 366.659 us; speedup vs baseline: 1.2730x; 1.2730x over previous
//
#include <hip/hip_runtime.h>

// MHA forward, MI355X/gfx950 — round 14 = EXACT REVERT to R11 (best, 367.9us).
// R12 (zero-barrier t-sliced pass 2): +17us. R13 (stores in phase G): +99us.
// Both pass-2 perturbations falsified -> R11's schedule is the structural
// floor for this decomposition. Locking it in as the final kernel.
// Stack: XCD swizzle (T1), nontemporal probs/out stores, counted-vmcnt pass 2
// (stores never barrier-drained more than FIFO-necessary), barrier-free
// 3-deep pass-1 ring, exp2 via builtin (log2e folded into Q pre-scale),
// 3 blocks/CU attn, wave-private K staging, V pre-transposed by QKV epilogue.

#define DEV __device__ __forceinline__

typedef __attribute__((ext_vector_type(8))) short short8;   // 8 bf16 (MFMA A/B frag)
typedef __attribute__((ext_vector_type(4))) float f32x4;    // MFMA C/D frag

DEV unsigned short f2b(float f) {   // f32 -> bf16 RNE
  union { float f; unsigned u; } v; v.f = f;
  unsigned r = v.u + 0x7fffu + ((v.u >> 16) & 1u);
  return (unsigned short)(r >> 16);
}
DEV unsigned pk2(float lo, float hi) {  // two f32 -> packed bf16x2
  return (unsigned)f2b(lo) | ((unsigned)f2b(hi) << 16);
}
#if __has_builtin(__builtin_amdgcn_exp2f)
DEV float exp2_fast(float x) { return __builtin_amdgcn_exp2f(x); }
#else
DEV float exp2_fast(float x) { return exp2f(x); }
#endif
DEV void gl_lds16(const void* g, void* l) {  // async global->LDS, dest = base + lane*16
  __builtin_amdgcn_global_load_lds(
      (const __attribute__((address_space(1))) void*)g,
      (__attribute__((address_space(3))) void*)l, 16, 0, 0);
}
DEV void bar_lgkm() { asm volatile("s_waitcnt lgkmcnt(0)\n\ts_barrier" ::: "memory"); }

__global__ void cvt_f32_bf16(const float* __restrict__ src, unsigned short* __restrict__ dst, int n) {
  int i = (blockIdx.x * blockDim.x + threadIdx.x) * 4;
  if (i >= n) return;
  float4 v = *(const float4*)(src + i);
  ushort4 o; o.x = f2b(v.x); o.y = f2b(v.y); o.z = f2b(v.z); o.w = f2b(v.w);
  *(ushort4*)(dst + i) = o;
}

// C = A @ B^T + bias; A[M][K], B[N][K] bf16. 128x128 tile, BK=64, 4 waves (2x2).
// MODE 0: fp32 C (ld=N, nontemporal).  MODE 1: QKV special — n<2048 -> bf16 Cqk
// (ld 2048, q cols scaled 0.125*log2e); n>=2048 -> V transposed into Vtg[bh][d][t].
template<int MODE>
__global__ __launch_bounds__(256, 2) void gemm_bt(
    const unsigned short* __restrict__ A,
    const unsigned short* __restrict__ B,
    const float* __restrict__ bias,
    float* __restrict__ Cf,
    unsigned short* __restrict__ Cqk,
    unsigned short* __restrict__ Vtg,
    int N, int K)
{
  constexpr int BK = 64;
  __shared__ __align__(16) unsigned short As[128*BK];
  __shared__ __align__(16) unsigned short Bs[128*BK];
  const int tid = threadIdx.x, lane = tid & 63, wid = tid >> 6;
  const int lhi = lane >> 4, llo = lane & 15;
  const int m0 = blockIdx.y * 128, n0 = blockIdx.x * 128;
  const int wr = wid >> 1, wc = wid & 1;

  f32x4 acc[4][4] = {};

  const int nsteps = K / BK;
  for (int kt = 0; kt < nsteps; ++kt) {
    __syncthreads();
#pragma unroll
    for (int s = 0; s < 4; ++s) {
      int u = wid*4 + s;
      int a = u*1024 + lane*16;
      int t = a >> 7;
      int cb = (a & 127) ^ ((t & 7) << 4);
      int e = kt*BK + (cb >> 1);
      gl_lds16(A + (size_t)(m0 + t)*K + e, (char*)As + u*1024);
      gl_lds16(B + (size_t)(n0 + t)*K + e, (char*)Bs + u*1024);
    }
    __syncthreads();
#pragma unroll
    for (int kk = 0; kk < 2; ++kk) {
      short8 af[4], bfr[4];
#pragma unroll
      for (int mf = 0; mf < 4; ++mf) {
        int row = wr*64 + mf*16 + llo;
        af[mf] = *(const short8*)((const char*)As + row*128 + ((kk*64 + lhi*16) ^ ((row & 7) << 4)));
      }
#pragma unroll
      for (int nf = 0; nf < 4; ++nf) {
        int row = wc*64 + nf*16 + llo;
        bfr[nf] = *(const short8*)((const char*)Bs + row*128 + ((kk*64 + lhi*16) ^ ((row & 7) << 4)));
      }
#pragma unroll
      for (int mf = 0; mf < 4; ++mf)
#pragma unroll
        for (int nf = 0; nf < 4; ++nf)
          acc[mf][nf] = __builtin_amdgcn_mfma_f32_16x16x32_bf16(af[mf], bfr[nf], acc[mf][nf], 0, 0, 0);
    }
  }
  // epilogue (C/D: row = lhi*4+r, col = llo)
  if (MODE == 0) {
#pragma unroll
    for (int mf = 0; mf < 4; ++mf)
#pragma unroll
      for (int nf = 0; nf < 4; ++nf) {
        int n = n0 + wc*64 + nf*16 + llo;
        float bv = bias[n];
#pragma unroll
        for (int r = 0; r < 4; ++r) {
          int m = m0 + wr*64 + mf*16 + lhi*4 + r;
          __builtin_nontemporal_store(acc[mf][nf][r] + bv, &Cf[(size_t)m*N + n]);
        }
      }
  } else {
    if (n0 < 2048) {  // Q/K region
#pragma unroll
      for (int mf = 0; mf < 4; ++mf)
#pragma unroll
        for (int nf = 0; nf < 4; ++nf) {
          int n = n0 + wc*64 + nf*16 + llo;
          float bv = bias[n];
          // q pre-scale folds softmax scale AND log2e (exp -> exp2)
          float sc = (n < 1024) ? 0.125f * 1.44269504088896f : 1.0f;
#pragma unroll
          for (int r = 0; r < 4; ++r) {
            int m = m0 + wr*64 + mf*16 + lhi*4 + r;
            Cqk[(size_t)m*2048 + n] = f2b((acc[mf][nf][r] + bv) * sc);
          }
        }
    } else {          // V region -> transposed Vtg[bh][d][t]
#pragma unroll
      for (int mf = 0; mf < 4; ++mf)
#pragma unroll
        for (int nf = 0; nf < 4; ++nf) {
          int n = n0 + wc*64 + nf*16 + llo;
          float bv = bias[n];
          int hh = (n - 2048) >> 6, d = (n - 2048) & 63;
          int m = m0 + wr*64 + mf*16 + lhi*4;
          int bb = m >> 11, t = m & 2047;
          ushort4 o;
          o.x = f2b(acc[mf][nf][0] + bv);
          o.y = f2b(acc[mf][nf][1] + bv);
          o.z = f2b(acc[mf][nf][2] + bv);
          o.w = f2b(acc[mf][nf][3] + bv);
          *(ushort4*)(Vtg + ((size_t)((bb << 4) + hh)*64 + d)*2048 + t) = o;
        }
    }
  }
}

// Fused attention. Block = (b,h,qt): 64 q-rows, 4 waves, 3 blocks/CU.
// Wave w owns t-cols [w*32,w*32+32) for scores (mfma(K,Q): D[t][q]) and
// q-rows [w*16,w*16+16) for PV (mfma(Vt,P): D[d][q]).
// K rows in LDS are wave-private (wave w stages & reads rows [32w,32w+32)).
__global__ __launch_bounds__(256, 3) void mha_fused(
    const unsigned short* __restrict__ qk,    // [8192][2048] bf16 (q scaled)
    const unsigned short* __restrict__ vtg,   // [64 bh][64 d][2048 t] bf16
    float* __restrict__ probs,                // [64 bh][2048][2048] f32
    unsigned short* __restrict__ attnb)       // [8192][1024] bf16
{
  constexpr int T = 2048, LD = 2048, QB = 64, TB = 128, NT = T / TB;
  __shared__ __align__(16) unsigned short Kslot[TB*64];   // 16 KB (ring0; pass2 K)
  __shared__ __align__(16) unsigned short Vslot[64*TB];   // 16 KB (ring1; pass2 V)
  __shared__ __align__(16) unsigned short Ps[QB*TB];      // 16 KB (ring2; prologue Q; pass2 P)
  __shared__ float lsum[4][QB];
  __shared__ float linv[QB];

  const int tid = threadIdx.x, lane = tid & 63, wid = tid >> 6;
  const int lhi = lane >> 4, llo = lane & 15;
  // XCD swizzle (T1): wgid = (bid%8)*256 + bid/8 (bijective, 2048%8==0).
  const int wg = ((blockIdx.x & 7) << 8) | (blockIdx.x >> 3);
  const int qt = wg & 31, bh = wg >> 5;
  const int bb = bh >> 4, h = bh & 15;
  const int q0 = qt * QB;
  const size_t tokQ = (size_t)bb*T + q0;

  auto stageK = [&](int tt, unsigned short* buf) {
#pragma unroll
    for (int s = 0; s < 4; ++s) {
      int u = wid*4 + s;
      int a = u*1024 + lane*16;
      int tr = a >> 7;
      int cb = (a & 127) ^ ((tr & 7) << 4);
      gl_lds16(qk + ((size_t)bb*T + tt*TB + tr)*LD + 1024 + h*64 + (cb >> 1),
               (char*)buf + u*1024);
    }
  };
  auto stageV = [&](int tt) {
#pragma unroll
    for (int s = 0; s < 4; ++s) {
      int u = wid*4 + s;
      int a = u*1024 + lane*16;
      int d = a >> 8;
      int cb = (a & 255) ^ ((d & 7) << 4);
      gl_lds16(vtg + ((size_t)bh*64 + d)*T + tt*TB + (cb >> 1),
               (char*)Vslot + u*1024);
    }
  };
  auto bsel = [&](int m) -> unsigned short* {
    return (m == 0) ? Kslot : ((m == 1) ? Vslot : Ps);
  };

  // ---- prologue: Q (into Ps region, 2/wave) + K0->Kslot + K1->Vslot ----
#pragma unroll
  for (int s = 0; s < 2; ++s) {
    int u = wid*2 + s;
    int a = u*1024 + lane*16;
    int tr = a >> 7;
    int cb = (a & 127) ^ ((tr & 7) << 4);
    gl_lds16(qk + (tokQ + tr)*LD + h*64 + (cb >> 1), (char*)Ps + u*1024);
  }
  stageK(0, Kslot);
  stageK(1, Vslot);
  asm volatile("s_waitcnt vmcnt(8)" ::: "memory");   // own Q done (K0,K1 in flight)
  __builtin_amdgcn_s_barrier();                      // publish Q

  // Q fragments in registers (loop-invariant)
  short8 qfr[4][2];
#pragma unroll
  for (int qf = 0; qf < 4; ++qf)
#pragma unroll
    for (int kk = 0; kk < 2; ++kk) {
      int row = qf*16 + llo;
      qfr[qf][kk] = *(const short8*)((const char*)Ps + row*128 + ((kk*64 + lhi*16) ^ ((row & 7) << 4)));
    }
  // all waves done reading Q from Ps before the ring stages K2 into Ps
  bar_lgkm();

  // ---------------- pass 1: denominators (3-deep rolled ring, no barriers) ----------------
  float part[4] = {0.f, 0.f, 0.f, 0.f};
  int m3 = 0;   // tt % 3
  int s3 = 2;   // (tt+2) % 3
  for (int tt = 0; tt < NT; ++tt) {
    if (tt + 2 < NT) stageK(tt + 2, bsel(s3));
    if (tt + 2 < NT)      asm volatile("s_waitcnt vmcnt(8)" ::: "memory");  // own K(tt) landed
    else if (tt + 1 < NT) asm volatile("s_waitcnt vmcnt(4)" ::: "memory");
    else                  asm volatile("s_waitcnt vmcnt(0)" ::: "memory");
    const unsigned short* cur = bsel(m3);
    f32x4 sacc[2][4] = {};
#pragma unroll
    for (int kk = 0; kk < 2; ++kk) {
      short8 kf[2];
#pragma unroll
      for (int tf = 0; tf < 2; ++tf) {
        int row = wid*32 + tf*16 + llo;
        kf[tf] = *(const short8*)((const char*)cur + row*128 + ((kk*64 + lhi*16) ^ ((row & 7) << 4)));
      }
#pragma unroll
      for (int tf = 0; tf < 2; ++tf)
#pragma unroll
        for (int qf = 0; qf < 4; ++qf)
          sacc[tf][qf] = __builtin_amdgcn_mfma_f32_16x16x32_bf16(kf[tf], qfr[qf][kk], sacc[tf][qf], 0, 0, 0);
    }
#pragma unroll
    for (int tf = 0; tf < 2; ++tf)
#pragma unroll
      for (int qf = 0; qf < 4; ++qf)
#pragma unroll
        for (int r = 0; r < 4; ++r)
          part[qf] += exp2_fast(sacc[tf][qf][r]);
    m3 = (m3 + 1 == 3) ? 0 : m3 + 1;
    s3 = (s3 + 1 == 3) ? 0 : s3 + 1;
  }

  // reduce: wave-local over lhi groups, then cross-wave via LDS
#pragma unroll
  for (int qf = 0; qf < 4; ++qf) {
    float v = part[qf];
    v += __shfl_xor(v, 16);
    v += __shfl_xor(v, 32);
    if (lhi == 0) lsum[wid][qf*16 + llo] = v;
  }
  bar_lgkm();                                 // lsum visible (all waves past pass 1)
  if (tid < QB) linv[tid] = 1.0f / (lsum[0][tid] + lsum[1][tid] + lsum[2][tid] + lsum[3][tid]);
  stageK(0, Kslot);                           // K0 for pass 2
  stageV(0);                                  // V0 for pass 2
  bar_lgkm();                                 // linv visible
  float lr[4];
#pragma unroll
  for (int qf = 0; qf < 4; ++qf) lr[qf] = linv[qf*16 + llo];

  // ---------------- pass 2: probs + PV (single K buffer, uniform vmcnt(12)) ----------------
  f32x4 pv[4] = {};
  for (int tt = 0; tt < NT; ++tt) {
    // top: own K(tt) landed. Steady state keeps stores(tt-1)8 + V(tt)4 = 12.
    if (tt == 0) asm volatile("s_waitcnt vmcnt(4)"  ::: "memory");
    else         asm volatile("s_waitcnt vmcnt(12)" ::: "memory");
    // A: scores from own Kslot rows
    f32x4 sacc[2][4] = {};
#pragma unroll
    for (int kk = 0; kk < 2; ++kk) {
      short8 kf[2];
#pragma unroll
      for (int tf = 0; tf < 2; ++tf) {
        int row = wid*32 + tf*16 + llo;
        kf[tf] = *(const short8*)((const char*)Kslot + row*128 + ((kk*64 + lhi*16) ^ ((row & 7) << 4)));
      }
#pragma unroll
      for (int tf = 0; tf < 2; ++tf)
#pragma unroll
        for (int qf = 0; qf < 4; ++qf)
          sacc[tf][qf] = __builtin_amdgcn_mfma_f32_16x16x32_bf16(kf[tf], qfr[qf][kk], sacc[tf][qf], 0, 0, 0);
    }
    // own ds_reads complete, then overwrite own K rows with K(tt+1)
    asm volatile("s_waitcnt lgkmcnt(0)" ::: "memory");
    __builtin_amdgcn_sched_barrier(0);
    stageK((tt + 1) & 15, Kslot);                    // dummy wrap at tt=15
    // B: exp2, normalize, pack Ps (b64 ds), nt-store probs directly
#pragma unroll
    for (int tf = 0; tf < 2; ++tf)
#pragma unroll
      for (int qf = 0; qf < 4; ++qf) {
        float p0 = exp2_fast(sacc[tf][qf][0]) * lr[qf];
        float p1 = exp2_fast(sacc[tf][qf][1]) * lr[qf];
        float p2 = exp2_fast(sacc[tf][qf][2]) * lr[qf];
        float p3 = exp2_fast(sacc[tf][qf][3]) * lr[qf];
        int q = qf*16 + llo;
        int t0 = wid*32 + tf*16 + lhi*4;
        uint2 w2; w2.x = pk2(p0, p1); w2.y = pk2(p2, p3);
        *(uint2*)((char*)Ps + q*256 + ((t0*2) ^ ((q & 7) << 4))) = w2;
        f32x4 pv4; pv4[0] = 8.f*p0; pv4[1] = 8.f*p1; pv4[2] = 8.f*p2; pv4[3] = 8.f*p3;
        __builtin_nontemporal_store(pv4,
            (f32x4*)&probs[((size_t)bh*T + q0 + q)*T + tt*TB + t0]);
      }
    // B1: V(tt) landed (keep K(tt+1)4 + stores(tt)8 = 12), publish Ps
    asm volatile("s_waitcnt vmcnt(12) lgkmcnt(0)\n\ts_barrier" ::: "memory");
    // D: PV (reads Ps + Vslot)
#pragma unroll
    for (int kk2 = 0; kk2 < 4; ++kk2) {
      int rq = wid*16 + llo;
      short8 pb = *(const short8*)((const char*)Ps + rq*256 + ((kk2*64 + lhi*16) ^ ((rq & 7) << 4)));
#pragma unroll
      for (int mf = 0; mf < 4; ++mf) {
        int rd = mf*16 + llo;
        short8 va = *(const short8*)((const char*)Vslot + rd*256 + ((kk2*64 + lhi*16) ^ ((rd & 7) << 4)));
        pv[mf] = __builtin_amdgcn_mfma_f32_16x16x32_bf16(va, pb, pv[mf], 0, 0, 0);
      }
    }
    // B2: all waves done with Ps/Vslot before overwrite next iter
    asm volatile("s_waitcnt lgkmcnt(0)\n\ts_barrier" ::: "memory");
    // F: issue next V
    stageV((tt + 1) & 15);                           // dummy wrap at tt=15
  }

  // attn out: D[d][q], lane has 4 consecutive d at q = wid*16+llo
#pragma unroll
  for (int mf = 0; mf < 4; ++mf) {
    int q = wid*16 + llo;
    int d0 = mf*16 + lhi*4;
    ushort4 o;
    o.x = f2b(pv[mf][0]); o.y = f2b(pv[mf][1]);
    o.z = f2b(pv[mf][2]); o.w = f2b(pv[mf][3]);
    *(ushort4*)(attnb + (tokQ + q)*1024 + h*64 + d0) = o;
  }
}

extern "C" void kernel_launch(void* const* d_in, const int* in_sizes, int n_in,
                              void* d_out, int out_size, void* d_ws, size_t ws_size,
                              hipStream_t stream) {
  (void)in_sizes; (void)n_in; (void)out_size; (void)ws_size;
  const float* x    = (const float*)d_in[0];
  const float* wqkv = (const float*)d_in[1];
  const float* bqkv = (const float*)d_in[2];
  const float* wout = (const float*)d_in[3];
  const float* bout = (const float*)d_in[4];

  constexpr int T = 2048, E = 1024;
  constexpr int M = 4 * T;
  constexpr size_t NX   = (size_t)M * E;
  constexpr size_t NW1  = (size_t)3 * E * E;
  constexpr size_t NW2  = (size_t)E * E;
  constexpr size_t NQK  = (size_t)M * 2048;
  constexpr size_t NVT  = (size_t)64 * 64 * T;

  char* ws = (char*)d_ws;
  unsigned short* xb    = (unsigned short*)ws;  ws += NX  * 2;
  unsigned short* wqkvb = (unsigned short*)ws;  ws += NW1 * 2;
  unsigned short* woutb = (unsigned short*)ws;  ws += NW2 * 2;
  unsigned short* qkb   = (unsigned short*)ws;  ws += NQK * 2;
  unsigned short* vtg   = (unsigned short*)ws;  ws += NVT * 2;
  unsigned short* attnb = (unsigned short*)ws;  ws += NX  * 2;

  cvt_f32_bf16<<<(int)(NX  / 1024), 256, 0, stream>>>(x,    xb,    (int)NX);
  cvt_f32_bf16<<<(int)(NW1 / 1024), 256, 0, stream>>>(wqkv, wqkvb, (int)NW1);
  cvt_f32_bf16<<<(int)(NW2 / 1024), 256, 0, stream>>>(wout, woutb, (int)NW2);

  gemm_bt<1><<<dim3(3*E/128, M/128), 256, 0, stream>>>(
      xb, wqkvb, bqkv, nullptr, qkb, vtg, 3*E, E);

  float* probsOut = (float*)d_out + NX;
  mha_fused<<<4*16*(T/64), 256, 0, stream>>>(qkb, vtg, probsOut, attnb);

  gemm_bt<0><<<dim3(E/128, M/128), 256, 0, stream>>>(
      attnb, woutb, bout, (float*)d_out, nullptr, nullptr, E, E);
}